// Round 1
// baseline (1859.745 us; speedup 1.0000x reference)
//
#include <hip/hip_runtime.h>

// GIN (2x GINE conv) restructured:
//   per layer: xW = in @ W1[:F] + b1          (GEMM, N x F x 128)
//              agg[i] = relu(xW[i] + w0 + w1) (self loop, ea = ones)
//              agg[dst] += relu(xW[src] + ea0*w0 + ea1*w1)  (edge scatter, atomics)
//              out = agg @ W2 + cnt * b2      (GEMM, N x 128 x 128), cnt = indeg+1
// Valid because gather commutes with the x-side matmul and segment_sum commutes
// with the (linear) W2 matmul; only the inner relu stays per-edge.

__global__ void cnt_init_kernel(int* cnt, int N) {
    int i = blockIdx.x * blockDim.x + threadIdx.x;
    if (i < N) cnt[i] = 1;  // self loop
}

__global__ void cnt_edge_kernel(const int* __restrict__ dst, int* cnt, int E) {
    int e = blockIdx.x * blockDim.x + threadIdx.x;
    if (e < E) atomicAdd(&cnt[dst[e]], 1);
}

// agg[i][j] = relu(xW[i][j] + we[j] + we[128+j])   (self-loop, also zero-init)
__global__ void selfloop_kernel(const float* __restrict__ xW,
                                const float* __restrict__ we,
                                float* __restrict__ agg, long total) {
    long idx = (long)blockIdx.x * blockDim.x + threadIdx.x;
    if (idx >= total) return;
    int j = (int)(idx & 127);
    float v = xW[idx] + we[j] + we[128 + j];
    agg[idx] = v > 0.f ? v : 0.f;
}

// one thread per (edge, j): agg[dst][j] += relu(xW[src][j] + ea0*w0[j] + ea1*w1[j])
__global__ void edge_kernel(const int* __restrict__ src, const int* __restrict__ dst,
                            const float* __restrict__ ea,
                            const float* __restrict__ xW,
                            const float* __restrict__ we,
                            float* __restrict__ agg, int E) {
    long idx = (long)blockIdx.x * blockDim.x + threadIdx.x;
    int e = (int)(idx >> 7);
    if (e >= E) return;
    int j = (int)(idx & 127);
    int s = src[e];
    int d = dst[e];
    float a0 = ea[2 * e];
    float a1 = ea[2 * e + 1];
    float v = xW[(long)s * 128 + j] + a0 * we[j] + a1 * we[128 + j];
    v = v > 0.f ? v : 0.f;
#if defined(__HIP_PLATFORM_AMD__)
    unsafeAtomicAdd(&agg[(long)d * 128 + j], v);
#else
    atomicAdd(&agg[(long)d * 128 + j], v);
#endif
}

// out[i][j] = in[i][:] @ W[:][j] + bias[j] * (cnt ? cnt[i] : 1), optional relu.
// 128 threads (one per output col j), ROWS rows per block. Input tile staged in
// LDS (broadcast float4 reads); W read from global (64 KB, L1/L2 resident).
template <int K>
__global__ __launch_bounds__(128) void gemm_kernel(
    const float* __restrict__ in, const float* __restrict__ W,
    const float* __restrict__ bias, const int* __restrict__ cnt,
    float* __restrict__ out, int N, int relu_flag) {
    constexpr int ROWS = 16;
    __shared__ float inl[ROWS][K];
    const int j = threadIdx.x;
    const long row0 = (long)blockIdx.x * ROWS;

    for (int idx = j; idx < ROWS * K; idx += 128) {
        int r = idx / K;
        int k = idx - r * K;
        long gr = row0 + r;
        inl[r][k] = (gr < (long)N) ? in[gr * K + k] : 0.f;
    }
    __syncthreads();

    float acc[ROWS];
#pragma unroll
    for (int r = 0; r < ROWS; r++) acc[r] = 0.f;

    for (int k4 = 0; k4 < K / 4; k4++) {
        float w0 = W[(4 * k4 + 0) * 128 + j];
        float w1 = W[(4 * k4 + 1) * 128 + j];
        float w2 = W[(4 * k4 + 2) * 128 + j];
        float w3 = W[(4 * k4 + 3) * 128 + j];
#pragma unroll
        for (int r = 0; r < ROWS; r++) {
            float4 iv = reinterpret_cast<const float4*>(&inl[r][0])[k4];
            acc[r] = fmaf(iv.x, w0, acc[r]);
            acc[r] = fmaf(iv.y, w1, acc[r]);
            acc[r] = fmaf(iv.z, w2, acc[r]);
            acc[r] = fmaf(iv.w, w3, acc[r]);
        }
    }

    float b = bias[j];
#pragma unroll
    for (int r = 0; r < ROWS; r++) {
        long gr = row0 + r;
        if (gr < (long)N) {
            float v = acc[r];
            v += cnt ? b * (float)cnt[gr] : b;
            if (relu_flag) v = fmaxf(v, 0.f);
            out[gr * 128 + j] = v;
        }
    }
}

extern "C" void kernel_launch(void* const* d_in, const int* in_sizes, int n_in,
                              void* d_out, int out_size, void* d_ws, size_t ws_size,
                              hipStream_t stream) {
    const float* x   = (const float*)d_in[0];
    const int*   ei  = (const int*)d_in[1];
    const float* ea  = (const float*)d_in[2];
    const float* W11 = (const float*)d_in[3];
    const float* b11 = (const float*)d_in[4];
    const float* W12 = (const float*)d_in[5];
    const float* b12 = (const float*)d_in[6];
    const float* W21 = (const float*)d_in[7];
    const float* b21 = (const float*)d_in[8];
    const float* W22 = (const float*)d_in[9];
    const float* b22 = (const float*)d_in[10];
    float* out = (float*)d_out;

    const int N = in_sizes[0] / 64;
    const int E = in_sizes[1] / 2;

    float* A = (float*)d_ws;                   // N*128 f32: xW buffer
    float* B = A + (size_t)N * 128;            // N*128 f32: agg buffer
    int* cnt = (int*)(B + (size_t)N * 128);    // N ints

    const int* src = ei;
    const int* dst = ei + E;

    const long totalN = (long)N * 128;
    const long totalE = (long)E * 128;
    const int initBlocks = (int)((totalN + 255) / 256);
    const int edgeBlocks = (int)((totalE + 255) / 256);
    const int gemmBlocks = (N + 15) / 16;

    // degree counts (+1 self loop) — shared by both layers
    cnt_init_kernel<<<(N + 255) / 256, 256, 0, stream>>>(cnt, N);
    cnt_edge_kernel<<<(E + 255) / 256, 256, 0, stream>>>(dst, cnt, E);

    // ---- layer 1 ----
    gemm_kernel<64><<<gemmBlocks, 128, 0, stream>>>(x, W11, b11, nullptr, A, N, 0);
    selfloop_kernel<<<initBlocks, 256, 0, stream>>>(A, W11 + 64 * 128, B, totalN);
    edge_kernel<<<edgeBlocks, 256, 0, stream>>>(src, dst, ea, A, W11 + 64 * 128, B, E);
    gemm_kernel<128><<<gemmBlocks, 128, 0, stream>>>(B, W12, b12, cnt, out, N, 1);

    // ---- layer 2 ----
    gemm_kernel<128><<<gemmBlocks, 128, 0, stream>>>(out, W21, b21, nullptr, A, N, 0);
    selfloop_kernel<<<initBlocks, 256, 0, stream>>>(A, W21 + 128 * 128, B, totalN);
    edge_kernel<<<edgeBlocks, 256, 0, stream>>>(src, dst, ea, A, W21 + 128 * 128, B, E);
    gemm_kernel<128><<<gemmBlocks, 128, 0, stream>>>(B, W22, b22, cnt, out, N, 0);
}

// Round 2
// 731.295 us; speedup vs baseline: 2.5431x; 2.5431x over previous
//
#include <hip/hip_runtime.h>

// GIN (2x GINE conv), CSR-gather version.
// Per layer:  A(bf16) = in @ W1[:F] + b1                      (GEMM)
//             B[i]    = relu(A[i]+w0+w1) + sum_{e: dst=i} relu(A[src_e]+a0*w0+a1*w1)
//                                                             (CSR gather, fp32 acc)
//             out     = B @ W2 + (deg[i]+1)*b2  (+relu)       (GEMM)
// CSR built on-device each call (ws is re-poisoned): degree -> scan -> fill.

typedef unsigned int uint;

static __device__ __forceinline__ unsigned short f2bf(float f) {
    uint u = __float_as_uint(f);
    uint r = (u + 0x7fffu + ((u >> 16) & 1u)) >> 16;
    return (unsigned short)r;
}

__global__ void zero_kernel(int* deg, int* fill, int N) {
    int i = blockIdx.x * blockDim.x + threadIdx.x;
    if (i < N) { deg[i] = 0; fill[i] = 0; }
}

__global__ void deg_kernel(const int* __restrict__ dst, int* deg, int E) {
    int e = blockIdx.x * blockDim.x + threadIdx.x;
    if (e < E) atomicAdd(&deg[dst[e]], 1);
}

// per-block inclusive scan (256 elems) -> ptr (as inclusive), block sums -> bsum
__global__ __launch_bounds__(256) void scan_block(const int* __restrict__ deg,
                                                  int* ptr, int* bsum, int N) {
    __shared__ int s[256];
    int i = blockIdx.x * 256 + threadIdx.x;
    int v = (i < N) ? deg[i] : 0;
    s[threadIdx.x] = v;
    __syncthreads();
    for (int off = 1; off < 256; off <<= 1) {
        int t = (threadIdx.x >= off) ? s[threadIdx.x - off] : 0;
        __syncthreads();
        s[threadIdx.x] += t;
        __syncthreads();
    }
    if (i < N) ptr[i] = s[threadIdx.x];
    if (threadIdx.x == 255) bsum[blockIdx.x] = s[255];
}

// single-block exclusive scan of block sums (nb <= 512)
__global__ __launch_bounds__(512) void scan_top(int* bsum, int nb) {
    __shared__ int s[512];
    int v = (threadIdx.x < nb) ? bsum[threadIdx.x] : 0;
    s[threadIdx.x] = v;
    __syncthreads();
    for (int off = 1; off < 512; off <<= 1) {
        int t = (threadIdx.x >= off) ? s[threadIdx.x - off] : 0;
        __syncthreads();
        s[threadIdx.x] += t;
        __syncthreads();
    }
    if (threadIdx.x < nb) bsum[threadIdx.x] = s[threadIdx.x] - v;  // exclusive
}

// ptr[i] (inclusive within block) -> global exclusive; ptr[N] = E
__global__ void scan_fix(int* ptr, const int* __restrict__ deg,
                         const int* __restrict__ bsum, int N, int E) {
    int i = blockIdx.x * blockDim.x + threadIdx.x;
    if (i < N) ptr[i] = ptr[i] - deg[i] + bsum[i >> 8];
    if (i == 0) ptr[N] = E;
}

__global__ void fill_csr(const int* __restrict__ src, const int* __restrict__ dst,
                         const float* __restrict__ ea,
                         const int* __restrict__ ptr, int* fill,
                         int* __restrict__ csr_src, uint* __restrict__ csr_ea, int E) {
    int e = blockIdx.x * blockDim.x + threadIdx.x;
    if (e >= E) return;
    int d = dst[e];
    int pos = ptr[d] + atomicAdd(&fill[d], 1);
    csr_src[pos] = src[e];
    uint lo = f2bf(ea[2 * e]);
    uint hi = f2bf(ea[2 * e + 1]);
    csr_ea[pos] = lo | (hi << 16);
}

// One wave (64 lanes) per node; lane t handles cols 2t, 2t+1 (one uint = bf16x2).
// B[i][:] = relu(A[i]+w0+w1) + sum_in-edges relu(A[src]+a0*w0+a1*w1), fp32 acc.
__global__ __launch_bounds__(256) void gather_kernel(
    const uint* __restrict__ Au,          // bf16x2 rows, 64 uints per node
    const int* __restrict__ ptr, const int* __restrict__ csr_src,
    const uint* __restrict__ csr_ea,
    const float* __restrict__ we,         // [2][128] fp32 edge-attr weight rows
    float* __restrict__ B, int N) {
    int node = blockIdx.x * 4 + (threadIdx.x >> 6);
    if (node >= N) return;
    int t = threadIdx.x & 63;
    int c = 2 * t;
    float w0x = we[c], w0y = we[c + 1];
    float w1x = we[128 + c], w1y = we[128 + c + 1];

    uint selfv = Au[(long)node * 64 + t];
    float sx = __uint_as_float(selfv << 16);
    float sy = __uint_as_float(selfv & 0xffff0000u);
    float ax = fmaxf(sx + w0x + w1x, 0.f);
    float ay = fmaxf(sy + w0y + w1y, 0.f);

    int k = ptr[node], end = ptr[node + 1];
    for (; k + 4 <= end; k += 4) {
        int s0 = csr_src[k], s1 = csr_src[k + 1], s2 = csr_src[k + 2], s3 = csr_src[k + 3];
        uint e0 = csr_ea[k], e1 = csr_ea[k + 1], e2 = csr_ea[k + 2], e3 = csr_ea[k + 3];
        uint r0 = Au[(long)s0 * 64 + t];
        uint r1 = Au[(long)s1 * 64 + t];
        uint r2 = Au[(long)s2 * 64 + t];
        uint r3 = Au[(long)s3 * 64 + t];
#define ACC(rv, ev)                                                      \
        {                                                                \
            float a0 = __uint_as_float((ev) << 16);                      \
            float a1 = __uint_as_float((ev) & 0xffff0000u);              \
            float vx = __uint_as_float((rv) << 16);                      \
            float vy = __uint_as_float((rv) & 0xffff0000u);              \
            vx = fmaf(a0, w0x, fmaf(a1, w1x, vx));                       \
            vy = fmaf(a0, w0y, fmaf(a1, w1y, vy));                       \
            ax += fmaxf(vx, 0.f);                                        \
            ay += fmaxf(vy, 0.f);                                        \
        }
        ACC(r0, e0) ACC(r1, e1) ACC(r2, e2) ACC(r3, e3)
    }
    for (; k < end; k++) {
        int s0 = csr_src[k];
        uint e0 = csr_ea[k];
        uint r0 = Au[(long)s0 * 64 + t];
        ACC(r0, e0)
    }
#undef ACC
    float2 o = make_float2(ax, ay);
    reinterpret_cast<float2*>(B)[(long)node * 64 + t] = o;
}

// out[i][j] = in[i][:] @ W[:][j] + bias[j]*(1 or deg[i]+1), optional relu,
// optional bf16 output. 128 threads (col j), 16 rows/block, input in LDS.
template <int K, bool OUT_BF16>
__global__ __launch_bounds__(128) void gemm_kernel(
    const float* __restrict__ in, const float* __restrict__ W,
    const float* __restrict__ bias, const int* __restrict__ ptr_for_cnt,
    void* __restrict__ out, int N, int relu_flag) {
    constexpr int ROWS = 16;
    __shared__ float inl[ROWS][K];
    const int j = threadIdx.x;
    const long row0 = (long)blockIdx.x * ROWS;

    for (int idx = j; idx < ROWS * K; idx += 128) {
        int r = idx / K;
        int k = idx - r * K;
        long gr = row0 + r;
        inl[r][k] = (gr < (long)N) ? in[gr * K + k] : 0.f;
    }
    __syncthreads();

    float acc[ROWS];
#pragma unroll
    for (int r = 0; r < ROWS; r++) acc[r] = 0.f;

    for (int k4 = 0; k4 < K / 4; k4++) {
        float w0 = W[(4 * k4 + 0) * 128 + j];
        float w1 = W[(4 * k4 + 1) * 128 + j];
        float w2 = W[(4 * k4 + 2) * 128 + j];
        float w3 = W[(4 * k4 + 3) * 128 + j];
#pragma unroll
        for (int r = 0; r < ROWS; r++) {
            float4 iv = reinterpret_cast<const float4*>(&inl[r][0])[k4];
            acc[r] = fmaf(iv.x, w0, acc[r]);
            acc[r] = fmaf(iv.y, w1, acc[r]);
            acc[r] = fmaf(iv.z, w2, acc[r]);
            acc[r] = fmaf(iv.w, w3, acc[r]);
        }
    }

    float b = bias[j];
#pragma unroll
    for (int r = 0; r < ROWS; r++) {
        long gr = row0 + r;
        if (gr < (long)N) {
            float v = acc[r];
            if (ptr_for_cnt) {
                int cnt = ptr_for_cnt[gr + 1] - ptr_for_cnt[gr] + 1;
                v += b * (float)cnt;
            } else {
                v += b;
            }
            if (relu_flag) v = fmaxf(v, 0.f);
            if (OUT_BF16)
                ((unsigned short*)out)[gr * 128 + j] = f2bf(v);
            else
                ((float*)out)[gr * 128 + j] = v;
        }
    }
}

extern "C" void kernel_launch(void* const* d_in, const int* in_sizes, int n_in,
                              void* d_out, int out_size, void* d_ws, size_t ws_size,
                              hipStream_t stream) {
    const float* x   = (const float*)d_in[0];
    const int*   ei  = (const int*)d_in[1];
    const float* ea  = (const float*)d_in[2];
    const float* W11 = (const float*)d_in[3];
    const float* b11 = (const float*)d_in[4];
    const float* W12 = (const float*)d_in[5];
    const float* b12 = (const float*)d_in[6];
    const float* W21 = (const float*)d_in[7];
    const float* b21 = (const float*)d_in[8];
    const float* W22 = (const float*)d_in[9];
    const float* b22 = (const float*)d_in[10];
    float* out = (float*)d_out;

    const int N = in_sizes[0] / 64;
    const int E = in_sizes[1] / 2;
    const int* src = ei;
    const int* dst = ei + E;

    // workspace layout
    char* p = (char*)d_ws;
    unsigned short* A_bf = (unsigned short*)p;  p += (size_t)N * 128 * 2;  // 25.6 MB
    float* B = (float*)p;                       p += (size_t)N * 128 * 4;  // 51.2 MB
    int*  csr_src = (int*)p;                    p += (size_t)E * 4;        //  6.4 MB
    uint* csr_ea  = (uint*)p;                   p += (size_t)E * 4;        //  6.4 MB
    int* ptr  = (int*)p;                        p += (size_t)(N + 1) * 4;
    int* deg  = (int*)p;                        p += (size_t)N * 4;
    int* fill = (int*)p;                        p += (size_t)N * 4;
    int* bsum = (int*)p;                        p += 512 * 4;

    const int nb = (N + 255) / 256;  // scan blocks (<=512)
    const int nodeBlocks = (N + 255) / 256;
    const int edgeBlocks = (E + 255) / 256;
    const int gemmBlocks = (N + 15) / 16;
    const int gatherBlocks = (N + 3) / 4;

    // ---- CSR build ----
    zero_kernel<<<nodeBlocks, 256, 0, stream>>>(deg, fill, N);
    deg_kernel<<<edgeBlocks, 256, 0, stream>>>(dst, deg, E);
    scan_block<<<nb, 256, 0, stream>>>(deg, ptr, bsum, N);
    scan_top<<<1, 512, 0, stream>>>(bsum, nb);
    scan_fix<<<nodeBlocks, 256, 0, stream>>>(ptr, deg, bsum, N, E);
    fill_csr<<<edgeBlocks, 256, 0, stream>>>(src, dst, ea, ptr, fill, csr_src, csr_ea, E);

    // ---- layer 1 ----
    gemm_kernel<64, true><<<gemmBlocks, 128, 0, stream>>>(x, W11, b11, nullptr, A_bf, N, 0);
    gather_kernel<<<gatherBlocks, 256, 0, stream>>>((const uint*)A_bf, ptr, csr_src, csr_ea,
                                                    W11 + 64 * 128, B, N);
    gemm_kernel<128, false><<<gemmBlocks, 128, 0, stream>>>(B, W12, b12, ptr, out, N, 1);

    // ---- layer 2 ----
    gemm_kernel<128, true><<<gemmBlocks, 128, 0, stream>>>(out, W21, b21, nullptr, A_bf, N, 0);
    gather_kernel<<<gatherBlocks, 256, 0, stream>>>((const uint*)A_bf, ptr, csr_src, csr_ea,
                                                    W21 + 128 * 128, B, N);
    gemm_kernel<128, false><<<gemmBlocks, 128, 0, stream>>>(B, W22, b22, ptr, out, N, 0);
}

// Round 3
// 561.340 us; speedup vs baseline: 3.3130x; 1.3028x over previous
//
#include <hip/hip_runtime.h>

// GIN (2x GINE conv): CSR gather + bf16 MFMA GEMMs.
// Per layer:  A(bf16) = in @ W1[:F] + b1                      (MFMA GEMM)
//             B(bf16) = relu(A[i]+w0+w1) + sum_e relu(A[src]+a0*w0+a1*w1)  (CSR gather, fp32 acc)
//             out     = B @ W2 + (deg+1)*b2 (+relu)           (MFMA GEMM)
// CSR rebuilt on-device each call (ws re-poisoned). Weights pre-transposed to
// bf16 col-major once per call so B-fragments are contiguous 16B loads.

typedef unsigned int uint;
typedef __attribute__((ext_vector_type(8))) short bf16x8;   // 8 bf16 = 4 VGPRs
typedef __attribute__((ext_vector_type(4))) float f32x4;

static __device__ __forceinline__ unsigned short f2bf(float f) {
    uint u = __float_as_uint(f);
    uint r = (u + 0x7fffu + ((u >> 16) & 1u)) >> 16;
    return (unsigned short)r;
}

// ---------------- CSR build ----------------

__global__ void zero_kernel(int* deg, int N) {
    int i = blockIdx.x * blockDim.x + threadIdx.x;
    if (i < N) deg[i] = 0;
}

__global__ void deg_kernel(const int* __restrict__ dst, int* deg, int E) {
    int e = blockIdx.x * blockDim.x + threadIdx.x;
    if (e < E) atomicAdd(&deg[dst[e]], 1);
}

__global__ __launch_bounds__(256) void scan_block(const int* __restrict__ deg,
                                                  int* ptr, int* bsum, int N) {
    __shared__ int s[256];
    int i = blockIdx.x * 256 + threadIdx.x;
    int v = (i < N) ? deg[i] : 0;
    s[threadIdx.x] = v;
    __syncthreads();
    for (int off = 1; off < 256; off <<= 1) {
        int t = (threadIdx.x >= off) ? s[threadIdx.x - off] : 0;
        __syncthreads();
        s[threadIdx.x] += t;
        __syncthreads();
    }
    if (i < N) ptr[i] = s[threadIdx.x];
    if (threadIdx.x == 255) bsum[blockIdx.x] = s[255];
}

__global__ __launch_bounds__(512) void scan_top(int* bsum, int nb) {
    __shared__ int s[512];
    int v = (threadIdx.x < nb) ? bsum[threadIdx.x] : 0;
    s[threadIdx.x] = v;
    __syncthreads();
    for (int off = 1; off < 512; off <<= 1) {
        int t = (threadIdx.x >= off) ? s[threadIdx.x - off] : 0;
        __syncthreads();
        s[threadIdx.x] += t;
        __syncthreads();
    }
    if (threadIdx.x < nb) bsum[threadIdx.x] = s[threadIdx.x] - v;  // exclusive
}

// ptr -> global exclusive; fill pre-seeded with ptr (saves a random read in fill_csr)
__global__ void scan_fix(int* ptr, int* fill, const int* __restrict__ deg,
                         const int* __restrict__ bsum, int N, int E) {
    int i = blockIdx.x * blockDim.x + threadIdx.x;
    if (i < N) {
        int v = ptr[i] - deg[i] + bsum[i >> 8];
        ptr[i] = v;
        fill[i] = v;
    }
    if (i == 0) ptr[N] = E;
}

__global__ void fill_csr(const int* __restrict__ src, const int* __restrict__ dst,
                         const float* __restrict__ ea, int* fill,
                         int2* __restrict__ csr, int E) {
    int e = blockIdx.x * blockDim.x + threadIdx.x;
    if (e >= E) return;
    int d = dst[e];
    int s = src[e];
    float2 a = reinterpret_cast<const float2*>(ea)[e];
    int pos = atomicAdd(&fill[d], 1);
    int2 v;
    v.x = s;
    v.y = (int)((uint)f2bf(a.x) | ((uint)f2bf(a.y) << 16));
    csr[pos] = v;  // single 8B scatter
}

// ---------------- weight prep: W[K][128] fp32 -> Wt[128][K] bf16 ----------------

__global__ void wprep_kernel(const float* __restrict__ W, unsigned short* __restrict__ Wt, int K) {
    int idx = blockIdx.x * 256 + threadIdx.x;
    if (idx >= K * 128) return;
    int k = idx >> 7, n = idx & 127;
    Wt[n * K + k] = f2bf(W[k * 128 + n]);
}

// ---------------- CSR gather (one wave per node, bf16 in/out, fp32 acc) ----------------

__global__ __launch_bounds__(256) void gather_kernel(
    const uint* __restrict__ Au,          // bf16x2 rows, 64 uints per node
    const int* __restrict__ ptr, const int2* __restrict__ csr,
    const float* __restrict__ we,         // [2][128] fp32 edge-attr weight rows
    uint* __restrict__ B, int N) {
    int node = blockIdx.x * 4 + (threadIdx.x >> 6);
    if (node >= N) return;
    int t = threadIdx.x & 63;
    int c = 2 * t;
    float w0x = we[c], w0y = we[c + 1];
    float w1x = we[128 + c], w1y = we[128 + c + 1];

    uint selfv = Au[(long)node * 64 + t];
    float sx = __uint_as_float(selfv << 16);
    float sy = __uint_as_float(selfv & 0xffff0000u);
    float ax = fmaxf(sx + w0x + w1x, 0.f);
    float ay = fmaxf(sy + w0y + w1y, 0.f);

    int k = ptr[node], end = ptr[node + 1];
#define ACC(rv, ev)                                                      \
    {                                                                    \
        float a0 = __uint_as_float(((uint)(ev)) << 16);                  \
        float a1 = __uint_as_float(((uint)(ev)) & 0xffff0000u);          \
        float vx = __uint_as_float((rv) << 16);                          \
        float vy = __uint_as_float((rv) & 0xffff0000u);                  \
        vx = fmaf(a0, w0x, fmaf(a1, w1x, vx));                           \
        vy = fmaf(a0, w0y, fmaf(a1, w1y, vy));                           \
        ax += fmaxf(vx, 0.f);                                            \
        ay += fmaxf(vy, 0.f);                                            \
    }
    for (; k + 4 <= end; k += 4) {
        int2 c0 = csr[k], c1 = csr[k + 1], c2 = csr[k + 2], c3 = csr[k + 3];
        uint r0 = Au[(long)c0.x * 64 + t];
        uint r1 = Au[(long)c1.x * 64 + t];
        uint r2 = Au[(long)c2.x * 64 + t];
        uint r3 = Au[(long)c3.x * 64 + t];
        ACC(r0, c0.y) ACC(r1, c1.y) ACC(r2, c2.y) ACC(r3, c3.y)
    }
    for (; k < end; k++) {
        int2 c0 = csr[k];
        uint r0 = Au[(long)c0.x * 64 + t];
        ACC(r0, c0.y)
    }
#undef ACC
    B[(long)node * 64 + t] = (uint)f2bf(ax) | ((uint)f2bf(ay) << 16);
}

// ---------------- MFMA GEMM: C[N][128] = A[N][K] @ W[K][128] + bias ----------------
// 256 thr = 4 waves; block tile 64 rows x 128 cols; wave w: col tiles {2w, 2w+1},
// all 4 row tiles. Fragments loaded straight from global (A bf16 row-major or fp32;
// Wt bf16 col-major). mfma_f32_16x16x32_bf16:
//   A[m=lane&15][k=quad*8+j], B[k=quad*8+j][n=lane&15], C: col=lane&15,row=quad*4+reg.

template <int K, bool IN_F32, bool OUT_BF16, bool USE_CNT, bool RELU>
__global__ __launch_bounds__(256) void gemm_mfma(
    const void* __restrict__ Ain, const unsigned short* __restrict__ Wt,
    const float* __restrict__ bias, const int* __restrict__ ptr,
    void* __restrict__ Cout, int N) {
    constexpr int KS = K / 32;
    const int wave = threadIdx.x >> 6;
    const int lane = threadIdx.x & 63;
    const int m = lane & 15, quad = lane >> 4;
    const long rowBase = (long)blockIdx.x * 64;

    bf16x8 bfrag[2][KS];
#pragma unroll
    for (int ct = 0; ct < 2; ct++) {
        int col = (wave * 2 + ct) * 16 + m;
#pragma unroll
        for (int ks = 0; ks < KS; ks++)
            bfrag[ct][ks] = *(const bf16x8*)(Wt + (long)col * K + ks * 32 + quad * 8);
    }

#pragma unroll
    for (int rt = 0; rt < 4; rt++) {
        long row = rowBase + rt * 16 + m;
        long rc = row < N ? row : (long)N - 1;  // clamped loads; stores guarded
        bf16x8 afrag[KS];
        if (IN_F32) {
            const float* arow = (const float*)Ain + rc * K;
#pragma unroll
            for (int ks = 0; ks < KS; ks++) {
                float4 lo = *(const float4*)(arow + ks * 32 + quad * 8);
                float4 hi = *(const float4*)(arow + ks * 32 + quad * 8 + 4);
                bf16x8 f;
                f[0] = (short)f2bf(lo.x); f[1] = (short)f2bf(lo.y);
                f[2] = (short)f2bf(lo.z); f[3] = (short)f2bf(lo.w);
                f[4] = (short)f2bf(hi.x); f[5] = (short)f2bf(hi.y);
                f[6] = (short)f2bf(hi.z); f[7] = (short)f2bf(hi.w);
                afrag[ks] = f;
            }
        } else {
            const unsigned short* arow = (const unsigned short*)Ain + rc * K;
#pragma unroll
            for (int ks = 0; ks < KS; ks++)
                afrag[ks] = *(const bf16x8*)(arow + ks * 32 + quad * 8);
        }

#pragma unroll
        for (int ct = 0; ct < 2; ct++) {
            f32x4 acc = {0.f, 0.f, 0.f, 0.f};
#pragma unroll
            for (int ks = 0; ks < KS; ks++)
                acc = __builtin_amdgcn_mfma_f32_16x16x32_bf16(afrag[ks], bfrag[ct][ks], acc, 0, 0, 0);

            int col = (wave * 2 + ct) * 16 + m;
            float b = bias[col];
#pragma unroll
            for (int r = 0; r < 4; r++) {
                long orow = rowBase + rt * 16 + quad * 4 + r;
                if (orow < N) {
                    float v = acc[r];
                    if (USE_CNT) v += b * (float)(ptr[orow + 1] - ptr[orow] + 1);
                    else v += b;
                    if (RELU) v = fmaxf(v, 0.f);
                    if (OUT_BF16) ((unsigned short*)Cout)[orow * 128 + col] = f2bf(v);
                    else ((float*)Cout)[orow * 128 + col] = v;
                }
            }
        }
    }
}

// ---------------- launch ----------------

extern "C" void kernel_launch(void* const* d_in, const int* in_sizes, int n_in,
                              void* d_out, int out_size, void* d_ws, size_t ws_size,
                              hipStream_t stream) {
    const float* x   = (const float*)d_in[0];
    const int*   ei  = (const int*)d_in[1];
    const float* ea  = (const float*)d_in[2];
    const float* W11 = (const float*)d_in[3];
    const float* b11 = (const float*)d_in[4];
    const float* W12 = (const float*)d_in[5];
    const float* b12 = (const float*)d_in[6];
    const float* W21 = (const float*)d_in[7];
    const float* b21 = (const float*)d_in[8];
    const float* W22 = (const float*)d_in[9];
    const float* b22 = (const float*)d_in[10];
    float* out = (float*)d_out;

    const int N = in_sizes[0] / 64;
    const int E = in_sizes[1] / 2;
    const int* src = ei;
    const int* dst = ei + E;

    // workspace layout (~91 MB)
    char* p = (char*)d_ws;
    unsigned short* A_bf = (unsigned short*)p;  p += (size_t)N * 128 * 2;  // 25.6 MB
    unsigned short* B_bf = (unsigned short*)p;  p += (size_t)N * 128 * 2;  // 25.6 MB
    unsigned short* H_bf = (unsigned short*)p;  p += (size_t)N * 128 * 2;  // 25.6 MB
    int2* csr = (int2*)p;                       p += (size_t)E * 8;        // 12.8 MB
    int* ptr  = (int*)p;                        p += (size_t)(N + 1) * 4;
    int* deg  = (int*)p;                        p += (size_t)N * 4;
    int* fill = (int*)p;                        p += (size_t)N * 4;
    int* bsum = (int*)p;                        p += 512 * 4;
    unsigned short* Wt11 = (unsigned short*)p;  p += (size_t)64 * 128 * 2;
    unsigned short* Wt12 = (unsigned short*)p;  p += (size_t)128 * 128 * 2;
    unsigned short* Wt21 = (unsigned short*)p;  p += (size_t)128 * 128 * 2;
    unsigned short* Wt22 = (unsigned short*)p;  p += (size_t)128 * 128 * 2;

    const int nb = (N + 255) / 256;
    const int nodeBlocks = (N + 255) / 256;
    const int edgeBlocks = (E + 255) / 256;
    const int gatherBlocks = (N + 3) / 4;
    const int gemmBlocks = (N + 63) / 64;

    // weight prep (independent of CSR build)
    wprep_kernel<<<(64 * 128 + 255) / 256, 256, 0, stream>>>(W11, Wt11, 64);
    wprep_kernel<<<(128 * 128 + 255) / 256, 256, 0, stream>>>(W12, Wt12, 128);
    wprep_kernel<<<(128 * 128 + 255) / 256, 256, 0, stream>>>(W21, Wt21, 128);
    wprep_kernel<<<(128 * 128 + 255) / 256, 256, 0, stream>>>(W22, Wt22, 128);

    // CSR build
    zero_kernel<<<nodeBlocks, 256, 0, stream>>>(deg, N);
    deg_kernel<<<edgeBlocks, 256, 0, stream>>>(dst, deg, E);
    scan_block<<<nb, 256, 0, stream>>>(deg, ptr, bsum, N);
    scan_top<<<1, 512, 0, stream>>>(bsum, nb);
    scan_fix<<<nodeBlocks, 256, 0, stream>>>(ptr, fill, deg, bsum, N, E);
    fill_csr<<<edgeBlocks, 256, 0, stream>>>(src, dst, ea, fill, csr, E);

    // ---- layer 1 ----
    gemm_mfma<64, true, true, false, false><<<gemmBlocks, 256, 0, stream>>>(
        x, Wt11, b11, nullptr, A_bf, N);
    gather_kernel<<<gatherBlocks, 256, 0, stream>>>((const uint*)A_bf, ptr, csr,
                                                    W11 + 64 * 128, (uint*)B_bf, N);
    gemm_mfma<128, false, true, true, true><<<gemmBlocks, 256, 0, stream>>>(
        B_bf, Wt12, b12, ptr, H_bf, N);

    // ---- layer 2 ----
    gemm_mfma<128, false, true, false, false><<<gemmBlocks, 256, 0, stream>>>(
        H_bf, Wt21, b21, nullptr, A_bf, N);
    gather_kernel<<<gatherBlocks, 256, 0, stream>>>((const uint*)A_bf, ptr, csr,
                                                    W21 + 128 * 128, (uint*)B_bf, N);
    gemm_mfma<128, false, false, true, false><<<gemmBlocks, 256, 0, stream>>>(
        B_bf, Wt22, b22, ptr, out, N);
}

// Round 4
// 437.232 us; speedup vs baseline: 4.2535x; 1.2839x over previous
//
#include <hip/hip_runtime.h>

// GIN (2x GINE conv): bucketed CSR build + CSR gather + bf16 MFMA GEMMs.
// CSR build: bin edges into 2048-node buckets (LDS tile sort, coalesced chunk
// appends), then per-bucket exact counting sort confined to one CU's L2.
// Per layer:  A(bf16) = in @ W1[:F] + b1                       (MFMA GEMM)
//             B(bf16) = relu(A[i]+w0+w1) + sum_e relu(A[src]+a0*w0+a1*w1)
//             out     = B @ W2 + (deg+1)*b2 (+relu)            (MFMA GEMM)

typedef unsigned int uint;
typedef __attribute__((ext_vector_type(8))) short bf16x8;
typedef __attribute__((ext_vector_type(4))) float f32x4;

#define BSHIFT 11            // 2048 nodes per bucket
#define BNODES (1 << BSHIFT)

static __device__ __forceinline__ unsigned short f2bf(float f) {
    uint u = __float_as_uint(f);
    uint r = (u + 0x7fffu + ((u >> 16) & 1u)) >> 16;
    return (unsigned short)r;
}

// ---------------- init ----------------

__global__ void init_kernel(int* bcnt, int* ptr, int N, int E) {
    int i = threadIdx.x;
    if (i < 64) bcnt[i] = 0;
    if (i == 0) ptr[N] = E;  // in case N is a multiple of BNODES
}

// ---------------- weight prep: W[K][128] fp32 -> Wt[128][K] bf16 ----------------

__global__ void wprep_all(const float* __restrict__ W11, const float* __restrict__ W12,
                          const float* __restrict__ W21, const float* __restrict__ W22,
                          unsigned short* Wt11, unsigned short* Wt12,
                          unsigned short* Wt21, unsigned short* Wt22) {
    int idx = blockIdx.x * 256 + threadIdx.x;
    const float* W; unsigned short* Wt; int K; int off;
    if (idx < 64 * 128)        { W = W11; Wt = Wt11; K = 64;  off = idx; }
    else if (idx < 192 * 128)  { W = W12; Wt = Wt12; K = 128; off = idx - 64 * 128; }
    else if (idx < 320 * 128)  { W = W21; Wt = Wt21; K = 128; off = idx - 192 * 128; }
    else if (idx < 448 * 128)  { W = W22; Wt = Wt22; K = 128; off = idx - 320 * 128; }
    else return;
    int k = off >> 7, n = off & 127;
    Wt[n * K + k] = f2bf(W[k * 128 + n]);
}

// ---------------- binning: tile-sort in LDS, coalesced chunk appends ----------------
// entry.x = src | (dloc << 17)   (src < 2^17, dloc < 2^11), entry.y = ea bf16x2

__global__ __launch_bounds__(256) void bin_kernel(
    const int* __restrict__ src, const int* __restrict__ dst,
    const float* __restrict__ ea, int* __restrict__ bcnt,
    int2* __restrict__ barr, int CAP, int E, int B) {
    __shared__ int hist[64];
    __shared__ int bbase[64];
    __shared__ int gbase[64];
    __shared__ int2 sorted[2048];
    __shared__ unsigned char bof[2048];
    const int tileBase = blockIdx.x * 2048;
    int n = E - tileBase; if (n > 2048) n = 2048; if (n <= 0) return;
    const int tid = threadIdx.x;
    if (tid < 64) hist[tid] = 0;
    __syncthreads();

    int2 ent[8]; int bk[8]; int rk[8];
#pragma unroll
    for (int k = 0; k < 8; k++) {
        int i = k * 256 + tid;
        bk[k] = -1;
        if (i < n) {
            int e = tileBase + i;
            int s = src[e], d = dst[e];
            float2 a = reinterpret_cast<const float2*>(ea)[e];
            int b = d >> BSHIFT;
            int dloc = d & (BNODES - 1);
            ent[k].x = s | (dloc << 17);
            ent[k].y = (int)((uint)f2bf(a.x) | ((uint)f2bf(a.y) << 16));
            bk[k] = b;
            rk[k] = atomicAdd(&hist[b], 1);
        }
    }
    __syncthreads();
    if (tid == 0) {
        int run = 0;
        for (int b = 0; b < B; b++) { bbase[b] = run; run += hist[b]; }
    }
    __syncthreads();
    if (tid < B && hist[tid] > 0) gbase[tid] = atomicAdd(&bcnt[tid], hist[tid]);
    __syncthreads();
#pragma unroll
    for (int k = 0; k < 8; k++) {
        if (bk[k] >= 0) {
            int p = bbase[bk[k]] + rk[k];
            sorted[p] = ent[k];
            bof[p] = (unsigned char)bk[k];
        }
    }
    __syncthreads();
    for (int i = tid; i < n; i += 256) {
        int b = bof[i];
        barr[(long)b * CAP + gbase[b] + (i - bbase[b])] = sorted[i];
    }
}

// ---------------- per-bucket exact CSR (one block per bucket) ----------------

__global__ __launch_bounds__(1024) void bucket_csr(
    const int2* __restrict__ barr, const int* __restrict__ bcnt,
    int CAP, int N, int B,
    int2* __restrict__ csr, int* __restrict__ ptr) {
    __shared__ int hist[BNODES];
    __shared__ int pairs[1024];
    __shared__ int lptr[BNODES];
    const int g = blockIdx.x;
    const int tid = threadIdx.x;
    const int cnt = bcnt[g];
    int base = 0;
    for (int b = 0; b < g; b++) base += bcnt[b];

    hist[tid] = 0; hist[tid + 1024] = 0;
    __syncthreads();
    const int2* my = barr + (long)g * CAP;
    for (int i = tid; i < cnt; i += 1024) {
        int dloc = ((uint)my[i].x) >> 17;
        atomicAdd(&hist[dloc], 1);
    }
    __syncthreads();
    // scan 2048 via pair-sum + Hillis-Steele over 1024
    int ps = hist[2 * tid] + hist[2 * tid + 1];
    pairs[tid] = ps;
    __syncthreads();
    for (int off = 1; off < 1024; off <<= 1) {
        int t = (tid >= off) ? pairs[tid - off] : 0;
        __syncthreads();
        pairs[tid] += t;
        __syncthreads();
    }
    int excl = pairs[tid] - ps;
    lptr[2 * tid] = excl;
    lptr[2 * tid + 1] = excl + hist[2 * tid];
    __syncthreads();
    for (int i = tid; i < BNODES; i += 1024) {
        long gnode = (long)g * BNODES + i;
        if (gnode <= (long)N) ptr[gnode] = base + lptr[i];
    }
    __syncthreads();
    for (int i = tid; i < cnt; i += 1024) {
        int2 v = my[i];
        int dloc = ((uint)v.x) >> 17;
        int pos = base + atomicAdd(&lptr[dloc], 1);
        int2 o; o.x = v.x & 0x1FFFF; o.y = v.y;
        csr[pos] = o;  // random only within this bucket's L2-resident slice
    }
}

// ---------------- CSR gather (one wave per node, bf16 in/out, fp32 acc) ----------------

__global__ __launch_bounds__(256) void gather_kernel(
    const uint* __restrict__ Au, const int* __restrict__ ptr,
    const int2* __restrict__ csr, const float* __restrict__ we,
    uint* __restrict__ B, int N) {
    int node = blockIdx.x * 4 + (threadIdx.x >> 6);
    if (node >= N) return;
    int t = threadIdx.x & 63;
    int c = 2 * t;
    float w0x = we[c], w0y = we[c + 1];
    float w1x = we[128 + c], w1y = we[128 + c + 1];

    uint selfv = Au[(long)node * 64 + t];
    float sx = __uint_as_float(selfv << 16);
    float sy = __uint_as_float(selfv & 0xffff0000u);
    float ax = fmaxf(sx + w0x + w1x, 0.f);
    float ay = fmaxf(sy + w0y + w1y, 0.f);

    int k = ptr[node], end = ptr[node + 1];
#define ACC(rv, ev)                                                      \
    {                                                                    \
        float a0 = __uint_as_float(((uint)(ev)) << 16);                  \
        float a1 = __uint_as_float(((uint)(ev)) & 0xffff0000u);          \
        float vx = __uint_as_float((rv) << 16);                          \
        float vy = __uint_as_float((rv) & 0xffff0000u);                  \
        vx = fmaf(a0, w0x, fmaf(a1, w1x, vx));                           \
        vy = fmaf(a0, w0y, fmaf(a1, w1y, vy));                           \
        ax += fmaxf(vx, 0.f);                                            \
        ay += fmaxf(vy, 0.f);                                            \
    }
    for (; k + 4 <= end; k += 4) {
        int2 c0 = csr[k], c1 = csr[k + 1], c2 = csr[k + 2], c3 = csr[k + 3];
        uint r0 = Au[(long)c0.x * 64 + t];
        uint r1 = Au[(long)c1.x * 64 + t];
        uint r2 = Au[(long)c2.x * 64 + t];
        uint r3 = Au[(long)c3.x * 64 + t];
        ACC(r0, c0.y) ACC(r1, c1.y) ACC(r2, c2.y) ACC(r3, c3.y)
    }
    for (; k < end; k++) {
        int2 c0 = csr[k];
        uint r0 = Au[(long)c0.x * 64 + t];
        ACC(r0, c0.y)
    }
#undef ACC
    B[(long)node * 64 + t] = (uint)f2bf(ax) | ((uint)f2bf(ay) << 16);
}

// ---------------- MFMA GEMM: C[N][128] = A[N][K] @ W[K][128] + bias ----------------

template <int K, bool IN_F32, bool OUT_BF16, bool USE_CNT, bool RELU>
__global__ __launch_bounds__(256) void gemm_mfma(
    const void* __restrict__ Ain, const unsigned short* __restrict__ Wt,
    const float* __restrict__ bias, const int* __restrict__ ptr,
    void* __restrict__ Cout, int N) {
    constexpr int KS = K / 32;
    const int wave = threadIdx.x >> 6;
    const int lane = threadIdx.x & 63;
    const int m = lane & 15, quad = lane >> 4;
    const long rowBase = (long)blockIdx.x * 64;

    bf16x8 bfrag[2][KS];
#pragma unroll
    for (int ct = 0; ct < 2; ct++) {
        int col = (wave * 2 + ct) * 16 + m;
#pragma unroll
        for (int ks = 0; ks < KS; ks++)
            bfrag[ct][ks] = *(const bf16x8*)(Wt + (long)col * K + ks * 32 + quad * 8);
    }

#pragma unroll
    for (int rt = 0; rt < 4; rt++) {
        long row = rowBase + rt * 16 + m;
        long rc = row < N ? row : (long)N - 1;
        bf16x8 afrag[KS];
        if (IN_F32) {
            const float* arow = (const float*)Ain + rc * K;
#pragma unroll
            for (int ks = 0; ks < KS; ks++) {
                float4 lo = *(const float4*)(arow + ks * 32 + quad * 8);
                float4 hi = *(const float4*)(arow + ks * 32 + quad * 8 + 4);
                bf16x8 f;
                f[0] = (short)f2bf(lo.x); f[1] = (short)f2bf(lo.y);
                f[2] = (short)f2bf(lo.z); f[3] = (short)f2bf(lo.w);
                f[4] = (short)f2bf(hi.x); f[5] = (short)f2bf(hi.y);
                f[6] = (short)f2bf(hi.z); f[7] = (short)f2bf(hi.w);
                afrag[ks] = f;
            }
        } else {
            const unsigned short* arow = (const unsigned short*)Ain + rc * K;
#pragma unroll
            for (int ks = 0; ks < KS; ks++)
                afrag[ks] = *(const bf16x8*)(arow + ks * 32 + quad * 8);
        }

#pragma unroll
        for (int ct = 0; ct < 2; ct++) {
            f32x4 acc = {0.f, 0.f, 0.f, 0.f};
#pragma unroll
            for (int ks = 0; ks < KS; ks++)
                acc = __builtin_amdgcn_mfma_f32_16x16x32_bf16(afrag[ks], bfrag[ct][ks], acc, 0, 0, 0);

            int col = (wave * 2 + ct) * 16 + m;
            float b = bias[col];
#pragma unroll
            for (int r = 0; r < 4; r++) {
                long orow = rowBase + rt * 16 + quad * 4 + r;
                if (orow < N) {
                    float v = acc[r];
                    if (USE_CNT) v += b * (float)(ptr[orow + 1] - ptr[orow] + 1);
                    else v += b;
                    if (RELU) v = fmaxf(v, 0.f);
                    if (OUT_BF16) ((unsigned short*)Cout)[orow * 128 + col] = f2bf(v);
                    else ((float*)Cout)[orow * 128 + col] = v;
                }
            }
        }
    }
}

// ---------------- launch ----------------

extern "C" void kernel_launch(void* const* d_in, const int* in_sizes, int n_in,
                              void* d_out, int out_size, void* d_ws, size_t ws_size,
                              hipStream_t stream) {
    const float* x   = (const float*)d_in[0];
    const int*   ei  = (const int*)d_in[1];
    const float* ea  = (const float*)d_in[2];
    const float* W11 = (const float*)d_in[3];
    const float* b11 = (const float*)d_in[4];
    const float* W12 = (const float*)d_in[5];
    const float* b12 = (const float*)d_in[6];
    const float* W21 = (const float*)d_in[7];
    const float* b21 = (const float*)d_in[8];
    const float* W22 = (const float*)d_in[9];
    const float* b22 = (const float*)d_in[10];
    float* out = (float*)d_out;

    const int N = in_sizes[0] / 64;
    const int E = in_sizes[1] / 2;
    const int* src = ei;
    const int* dst = ei + E;

    const int B = (N + BNODES - 1) >> BSHIFT;          // buckets
    const int CAP = E / B + 4096;                      // per-bucket capacity

    // workspace layout (~65 MB); bucket storage aliases the B feature buffer
    char* p = (char*)d_ws;
    unsigned short* A_bf = (unsigned short*)p;  p += (size_t)N * 128 * 2;  // 25.6 MB
    unsigned short* B_bf = (unsigned short*)p;                             // 25.6 MB, aliased:
    int2* barr = (int2*)B_bf;                   p += (size_t)N * 128 * 2;  //   barr = B*CAP*8 <= 14.5 MB
    int2* csr  = (int2*)p;                      p += (size_t)E * 8;        // 12.8 MB
    int* ptr   = (int*)p;                       p += (size_t)(N + 1) * 4;
    int* bcnt  = (int*)p;                       p += 64 * 4;
    unsigned short* Wt11 = (unsigned short*)p;  p += (size_t)64 * 128 * 2;
    unsigned short* Wt12 = (unsigned short*)p;  p += (size_t)128 * 128 * 2;
    unsigned short* Wt21 = (unsigned short*)p;  p += (size_t)128 * 128 * 2;
    unsigned short* Wt22 = (unsigned short*)p;

    const int binBlocks = (E + 2047) / 2048;
    const int gatherBlocks = (N + 3) / 4;
    const int gemmBlocks = (N + 63) / 64;

    init_kernel<<<1, 64, 0, stream>>>(bcnt, ptr, N, E);
    wprep_all<<<(448 * 128 + 255) / 256, 256, 0, stream>>>(W11, W12, W21, W22,
                                                           Wt11, Wt12, Wt21, Wt22);

    // CSR build: bin -> per-bucket exact sort (ptr comes out of it for free)
    bin_kernel<<<binBlocks, 256, 0, stream>>>(src, dst, ea, bcnt, barr, CAP, E, B);
    bucket_csr<<<B, 1024, 0, stream>>>(barr, bcnt, CAP, N, B, csr, ptr);

    // ---- layer 1 ----   (barr region is free now; B_bf reuses it)
    gemm_mfma<64, true, true, false, false><<<gemmBlocks, 256, 0, stream>>>(
        x, Wt11, b11, nullptr, A_bf, N);
    gather_kernel<<<gatherBlocks, 256, 0, stream>>>((const uint*)A_bf, ptr, csr,
                                                    W11 + 64 * 128, (uint*)B_bf, N);
    gemm_mfma<128, false, true, true, true><<<gemmBlocks, 256, 0, stream>>>(
        B_bf, Wt12, b12, ptr, A_bf, N);   // H reuses A

    // ---- layer 2 ----
    gemm_mfma<128, false, true, false, false><<<gemmBlocks, 256, 0, stream>>>(
        A_bf, Wt21, b21, nullptr, B_bf, N);
    gather_kernel<<<gatherBlocks, 256, 0, stream>>>((const uint*)B_bf, ptr, csr,
                                                    W21 + 128 * 128, (uint*)A_bf, N);
    gemm_mfma<128, false, false, true, false><<<gemmBlocks, 256, 0, stream>>>(
        A_bf, Wt22, b22, ptr, out, N);
}